// Round 4
// baseline (242.344 us; speedup 1.0000x reference)
//
#include <hip/hip_runtime.h>
#include <stdint.h>

// ---- problem constants ----
constexpr int Mdim = 8192;
constexpr int Ndim = 4096;
constexpr int Kdim = 4096;
constexpr int NT = Kdim / 128;  // 32 K-tiles of BK=128

#define ISF        ((float)(2.0 / 255.0))          // IN_SCALE
#define OUT_SCALE  ((float)(2.0 / 255.0 * 0.01))   // IN_SCALE * W_SCALE
#define BSCALE     0.01f
// IN_ZP = 127 (the +1e-12 pulls 127.5 below the .5 boundary). x_shifted in [-127,128]
// doesn't fit int8 -> compute u = x_q - 128 in [-128,127]; acc = GEMM(u,w) + rowsum_w[n].

typedef int i32x4 __attribute__((ext_vector_type(4)));

// ---------------- pre-pass 1: quantize x_float -> int8
__global__ __launch_bounds__(256) void quantize_x(const float* __restrict__ x,
                                                  int* __restrict__ x8,
                                                  int ngroups) {
  int idx = blockIdx.x * 256 + threadIdx.x;
  int stride = gridDim.x * 256;
  for (int g = idx; g < ngroups; g += stride) {
    float4 v = reinterpret_cast<const float4*>(x)[g];
    int a0 = (int)rintf(v.x / ISF + 127.0f);
    int a1 = (int)rintf(v.y / ISF + 127.0f);
    int a2 = (int)rintf(v.z / ISF + 127.0f);
    int a3 = (int)rintf(v.w / ISF + 127.0f);
    a0 = a0 < 0 ? 0 : (a0 > 255 ? 255 : a0); a0 -= 128;
    a1 = a1 < 0 ? 0 : (a1 > 255 ? 255 : a1); a1 -= 128;
    a2 = a2 < 0 ? 0 : (a2 > 255 ? 255 : a2); a2 -= 128;
    a3 = a3 < 0 ? 0 : (a3 > 255 ? 255 : a3); a3 -= 128;
    x8[g] = (a0 & 0xff) | ((a1 & 0xff) << 8) | ((a2 & 0xff) << 16) |
            (int)(((unsigned)(a3 & 0xff)) << 24);
  }
}

// ---------------- pre-pass 2: w_q int32 -> int8 packed, fused per-row sum
__global__ __launch_bounds__(256) void convert_w(const int* __restrict__ wq,
                                                 int* __restrict__ w8,
                                                 int* __restrict__ wsum) {
  int row = blockIdx.x;
  const int4* src = reinterpret_cast<const int4*>(wq + (size_t)row * Kdim);
  int* dst = w8 + (size_t)row * (Kdim / 4);
  int s = 0;
#pragma unroll
  for (int i = 0; i < 4; ++i) {
    int idx = i * 256 + threadIdx.x;
    int4 v = src[idx];
    s += v.x + v.y + v.z + v.w;
    dst[idx] = (v.x & 0xff) | ((v.y & 0xff) << 8) | ((v.z & 0xff) << 16) |
               (int)(((unsigned)(v.w & 0xff)) << 24);
  }
  __shared__ int red[256];
  red[threadIdx.x] = s;
  __syncthreads();
  for (int off = 128; off; off >>= 1) {
    if ((int)threadIdx.x < off) red[threadIdx.x] += red[threadIdx.x + off];
    __syncthreads();
  }
  if (threadIdx.x == 0) wsum[row] = red[0];
}

// ---------------- 256x256 16x16x64 i8 GEMM, frag-reads pipelined 1 phase ahead,
// 1 barrier/phase (4/K-tile), counted vmcnt(4), T5 setprio.
// LDS: A buf0 @0, A buf1 @32768, B buf0 @65536, B buf1 @98304  (128 KiB)
#define AS1C const __attribute__((address_space(1))) void*
#define AS3  __attribute__((address_space(3))) void*
#define GLL(src, dst) __builtin_amdgcn_global_load_lds((AS1C)(src), (AS3)(dst), 16, 0, 0)
#define BAR() asm volatile("s_barrier" ::: "memory")
#define VMC(N) asm volatile("s_waitcnt vmcnt(" #N ")" ::: "memory")
#define MFMA(a, b, c) __builtin_amdgcn_mfma_i32_16x16x64_i8(a, b, c, 0, 0, 0)

__global__ __launch_bounds__(512, 2) void gemm_i8_pl(const int8_t* __restrict__ A8,
                                                     const int8_t* __restrict__ B8,
                                                     const int* __restrict__ wsum,
                                                     const int* __restrict__ bq,
                                                     float* __restrict__ out) {
  __shared__ uint8_t lds[131072];

  // bijective XCD swizzle: 512 blocks, 512 % 8 == 0
  int bid = blockIdx.x;
  int wg = (bid & 7) * 64 + (bid >> 3);
  int bm = wg >> 4;  // 32 row-tiles
  int bn = wg & 15;  // 16 col-tiles

  const int tid = threadIdx.x;
  const int lane = tid & 63;
  const int wv = tid >> 6;   // 0..7
  const int wr = wv >> 2;    // 0..1 : 128-row half of C
  const int wc = wv & 3;     // 0..3 : 64-col quarter of C
  const int l15 = lane & 15, hi = lane >> 4;

  // staging source (per lane): row-chunk r3, slot s3, pre-swizzled col (rule #21)
  const int r3 = lane >> 3, s3 = lane & 7;
  const int swcol = (s3 ^ r3) << 4;
  const size_t aoff = (size_t)(bm * 256 + wv * 8 + r3) * Kdim + swcol;
  const size_t boff = (size_t)(bn * 256 + wv * 8 + r3) * Kdim + swcol;
  const int ldsw = wv * 1024;

#define ISSUE_A(P, t, half) do { \
    GLL(A8 + aoff + (size_t)(t) * 128 + (size_t)((half) * 128) * Kdim, \
        &lds[(P) * 32768 + (half) * 16384 + ldsw]); \
    GLL(A8 + aoff + (size_t)(t) * 128 + (size_t)((half) * 128 + 64) * Kdim, \
        &lds[(P) * 32768 + (half) * 16384 + 8192 + ldsw]); \
  } while (0)
#define ISSUE_B(P, t, half) do { \
    GLL(B8 + boff + (size_t)(t) * 128 + (size_t)((half) * 128) * Kdim, \
        &lds[65536 + (P) * 32768 + (half) * 16384 + ldsw]); \
    GLL(B8 + boff + (size_t)(t) * 128 + (size_t)((half) * 128 + 64) * Kdim, \
        &lds[65536 + (P) * 32768 + (half) * 16384 + 8192 + ldsw]); \
  } while (0)

  // fragment addressing (identical to the 131us round-2 kernel; measured 0 conflicts)
  const int aRow = (wr * 128 + l15) * 128;
  const int bRow = (wc * 64 + l15) * 128;
  const int sl0 = (hi ^ (l15 & 7)) << 4;
  const int sl1 = ((4 + hi) ^ (l15 & 7)) << 4;

#define LDA(P, i, ks) (*reinterpret_cast<const i32x4*>( \
    &lds[(P) * 32768 + aRow + (i) * 2048 + ((ks) ? sl1 : sl0)]))
#define LDB(P, j, ks) (*reinterpret_cast<const i32x4*>( \
    &lds[65536 + (P) * 32768 + bRow + (j) * 2048 + ((ks) ? sl1 : sl0)]))

  i32x4 acc[8][4];
#pragma unroll
  for (int i = 0; i < 8; ++i)
#pragma unroll
    for (int j = 0; j < 4; ++j) acc[i][j] = (i32x4){0, 0, 0, 0};

  // register frag sets (read one phase ahead of use)
  i32x4 a0[8], a1[8], b1_[2], b2_[2], b3_[2], b4_[2];

  // prologue: tile0 A+B (8 GLL) + tile1 A (4 GLL); vmcnt(4) retires tile0's 8.
  ISSUE_A(0, 0, 0); ISSUE_A(0, 0, 1);
  ISSUE_B(0, 0, 0); ISSUE_B(0, 0, 1);
  ISSUE_A(1, 1, 0); ISSUE_A(1, 1, 1);
  VMC(4);
  BAR();
  // read tile0.p1 frags
#pragma unroll
  for (int i = 0; i < 8; ++i) a0[i] = LDA(0, i, 0);
  b1_[0] = LDB(0, 0, 0); b1_[1] = LDB(0, 1, 0);

  // Per tile t (buf P), 4 phases, 1 barrier each. Frags for phase i+1 read during
  // phase i (post-barrier, pre-MFMA). GLL: p1/p2 -> B(t+1) into P^1; p4 -> A(t+2)
  // into P (A-region of P free: a1 reads all issued before BAR(p3)).
  // vmcnt(4) at p4 guarantees A(t+1),B(t+1) landed (4 newest = A(t+2)) before the
  // post-barrier cross-tile reads of buf P^1. Never drains to 0 in steady state.
#define TILE(P, t, DOB, DOA, VM4, VM0, CROSS) do { \
    /* phase 1: mfma a0 x b1_ -> acc[][0,1] */ \
    if (DOB) ISSUE_B((P) ^ 1, (t) + 1, 0); \
    BAR(); \
    b2_[0] = LDB(P, 2, 0); b2_[1] = LDB(P, 3, 0); \
    __builtin_amdgcn_s_setprio(1); \
    _Pragma("unroll") for (int i = 0; i < 8; ++i) { \
      acc[i][0] = MFMA(a0[i], b1_[0], acc[i][0]); \
      acc[i][1] = MFMA(a0[i], b1_[1], acc[i][1]); } \
    __builtin_amdgcn_s_setprio(0); \
    /* phase 2: mfma a0 x b2_ -> acc[][2,3] */ \
    if (DOB) ISSUE_B((P) ^ 1, (t) + 1, 1); \
    BAR(); \
    _Pragma("unroll") for (int i = 0; i < 8; ++i) a1[i] = LDA(P, i, 1); \
    b3_[0] = LDB(P, 0, 1); b3_[1] = LDB(P, 1, 1); \
    __builtin_amdgcn_s_setprio(1); \
    _Pragma("unroll") for (int i = 0; i < 8; ++i) { \
      acc[i][2] = MFMA(a0[i], b2_[0], acc[i][2]); \
      acc[i][3] = MFMA(a0[i], b2_[1], acc[i][3]); } \
    __builtin_amdgcn_s_setprio(0); \
    /* phase 3: mfma a1 x b3_ -> acc[][0,1] */ \
    BAR(); \
    b4_[0] = LDB(P, 2, 1); b4_[1] = LDB(P, 3, 1); \
    __builtin_amdgcn_s_setprio(1); \
    _Pragma("unroll") for (int i = 0; i < 8; ++i) { \
      acc[i][0] = MFMA(a1[i], b3_[0], acc[i][0]); \
      acc[i][1] = MFMA(a1[i], b3_[1], acc[i][1]); } \
    __builtin_amdgcn_s_setprio(0); \
    /* phase 4: mfma a1 x b4_ -> acc[][2,3]; cross-tile frag reads */ \
    if (DOA) { ISSUE_A(P, (t) + 2, 0); ISSUE_A(P, (t) + 2, 1); } \
    if (VM4) VMC(4); \
    if (VM0) VMC(0); \
    BAR(); \
    if (CROSS) { \
      _Pragma("unroll") for (int i = 0; i < 8; ++i) a0[i] = LDA((P) ^ 1, i, 0); \
      b1_[0] = LDB((P) ^ 1, 0, 0); b1_[1] = LDB((P) ^ 1, 1, 0); } \
    __builtin_amdgcn_s_setprio(1); \
    _Pragma("unroll") for (int i = 0; i < 8; ++i) { \
      acc[i][2] = MFMA(a1[i], b4_[0], acc[i][2]); \
      acc[i][3] = MFMA(a1[i], b4_[1], acc[i][3]); } \
    __builtin_amdgcn_s_setprio(0); \
  } while (0)

  for (int it = 0; it < NT / 2 - 1; ++it) {  // t = 0..29
    TILE(0, 2 * it, 1, 1, 1, 0, 1);
    TILE(1, 2 * it + 1, 1, 1, 1, 0, 1);
  }
  // t=30: issue B(31) only; nothing newer than B(31) -> vmcnt(0) before cross-reads.
  TILE(0, 30, 1, 0, 0, 1, 1);
  // t=31: pure consume.
  TILE(1, 31, 0, 0, 0, 0, 0);

  // epilogue: C/D layout col = lane&15, row = (lane>>4)*4 + reg
#pragma unroll
  for (int j = 0; j < 4; ++j) {
    int col = bn * 256 + wc * 64 + j * 16 + l15;
    float fb = (float)bq[col] * BSCALE;
    int ws = wsum[col];
#pragma unroll
    for (int i = 0; i < 8; ++i) {
      int rbase = bm * 256 + wr * 128 + i * 16 + hi * 4;
#pragma unroll
      for (int p = 0; p < 4; ++p)
        out[(size_t)(rbase + p) * Ndim + col] = (float)(acc[i][j][p] + ws) * OUT_SCALE + fb;
    }
  }
#undef TILE
#undef ISSUE_A
#undef ISSUE_B
#undef LDA
#undef LDB
}

// ---------------- naive fallback (only if ws_size is unexpectedly small)
__global__ void fallback_kernel(const float* __restrict__ x, const int* __restrict__ wq,
                                const int* __restrict__ bq, float* __restrict__ out) {
  int col = blockIdx.x * 16 + (threadIdx.x & 15);
  int row = blockIdx.y * 16 + (threadIdx.x >> 4);
  const float* xr = x + (size_t)row * Kdim;
  const int* wr_ = wq + (size_t)col * Kdim;
  int acc = 0;
  for (int k = 0; k < Kdim; ++k) {
    int v = (int)rintf(xr[k] / ISF + 127.0f);
    v = v < 0 ? 0 : (v > 255 ? 255 : v);
    acc += (v - 127) * wr_[k];
  }
  out[(size_t)row * Ndim + col] = (float)acc * OUT_SCALE + (float)bq[col] * BSCALE;
}

extern "C" void kernel_launch(void* const* d_in, const int* in_sizes, int n_in,
                              void* d_out, int out_size, void* d_ws, size_t ws_size,
                              hipStream_t stream) {
  const float* x = (const float*)d_in[0];
  const int* wq = (const int*)d_in[1];
  const int* bq = (const int*)d_in[2];
  float* out = (float*)d_out;

  const size_t x8_bytes = (size_t)Mdim * Kdim;  // 32 MiB
  const size_t w8_bytes = (size_t)Ndim * Kdim;  // 16 MiB
  const size_t ws_need = x8_bytes + w8_bytes + (size_t)Ndim * sizeof(int);

  if (ws_size >= ws_need) {
    int8_t* x8 = (int8_t*)d_ws;
    int8_t* w8 = x8 + x8_bytes;
    int* wsum = (int*)(w8 + w8_bytes);

    quantize_x<<<2048, 256, 0, stream>>>(x, (int*)x8, Mdim * Kdim / 4);
    convert_w<<<Ndim, 256, 0, stream>>>(wq, (int*)w8, wsum);
    gemm_i8_pl<<<(Mdim / 256) * (Ndim / 256), 512, 0, stream>>>(x8, w8, wsum, bq, out);
  } else {
    dim3 grid(Ndim / 16, Mdim / 16);
    fallback_kernel<<<grid, 256, 0, stream>>>(x, wq, bq, out);
  }
}

// Round 5
// 203.456 us; speedup vs baseline: 1.1911x; 1.1911x over previous
//
#include <hip/hip_runtime.h>
#include <stdint.h>

// ---- problem constants ----
constexpr int Mdim = 8192;
constexpr int Ndim = 4096;
constexpr int Kdim = 4096;
constexpr int NSTEP = Kdim / 64;  // 64 K-steps of BK=64

#define ISF        ((float)(2.0 / 255.0))          // IN_SCALE
#define OUT_SCALE  ((float)(2.0 / 255.0 * 0.01))   // IN_SCALE * W_SCALE
#define BSCALE     0.01f
// IN_ZP = 127 (the +1e-12 pulls 127.5 below the .5 boundary). x_shifted in [-127,128]
// doesn't fit int8 -> compute u = x_q - 128 in [-128,127]; acc = GEMM(u,w) + rowsum_w[n].

typedef int i32x4 __attribute__((ext_vector_type(4)));

// ---------------- pre-pass 1: quantize x_float -> int8
__global__ __launch_bounds__(256) void quantize_x(const float* __restrict__ x,
                                                  int* __restrict__ x8,
                                                  int ngroups) {
  int idx = blockIdx.x * 256 + threadIdx.x;
  int stride = gridDim.x * 256;
  for (int g = idx; g < ngroups; g += stride) {
    float4 v = reinterpret_cast<const float4*>(x)[g];
    int a0 = (int)rintf(v.x / ISF + 127.0f);
    int a1 = (int)rintf(v.y / ISF + 127.0f);
    int a2 = (int)rintf(v.z / ISF + 127.0f);
    int a3 = (int)rintf(v.w / ISF + 127.0f);
    a0 = a0 < 0 ? 0 : (a0 > 255 ? 255 : a0); a0 -= 128;
    a1 = a1 < 0 ? 0 : (a1 > 255 ? 255 : a1); a1 -= 128;
    a2 = a2 < 0 ? 0 : (a2 > 255 ? 255 : a2); a2 -= 128;
    a3 = a3 < 0 ? 0 : (a3 > 255 ? 255 : a3); a3 -= 128;
    x8[g] = (a0 & 0xff) | ((a1 & 0xff) << 8) | ((a2 & 0xff) << 16) |
            (int)(((unsigned)(a3 & 0xff)) << 24);
  }
}

// ---------------- pre-pass 2: w_q int32 -> int8 packed, fused per-row sum
__global__ __launch_bounds__(256) void convert_w(const int* __restrict__ wq,
                                                 int* __restrict__ w8,
                                                 int* __restrict__ wsum) {
  int row = blockIdx.x;
  const int4* src = reinterpret_cast<const int4*>(wq + (size_t)row * Kdim);
  int* dst = w8 + (size_t)row * (Kdim / 4);
  int s = 0;
#pragma unroll
  for (int i = 0; i < 4; ++i) {
    int idx = i * 256 + threadIdx.x;
    int4 v = src[idx];
    s += v.x + v.y + v.z + v.w;
    dst[idx] = (v.x & 0xff) | ((v.y & 0xff) << 8) | ((v.z & 0xff) << 16) |
               (int)(((unsigned)(v.w & 0xff)) << 24);
  }
  __shared__ int red[256];
  red[threadIdx.x] = s;
  __syncthreads();
  for (int off = 128; off; off >>= 1) {
    if ((int)threadIdx.x < off) red[threadIdx.x] += red[threadIdx.x + off];
    __syncthreads();
  }
  if (threadIdx.x == 0) wsum[row] = red[0];
}

// ---------------- 256x128 block / BK=64 / 4 waves / 64 KiB LDS -> 2 blocks/CU.
// Overlap via two independent blocks per CU (independent barrier domains).
// A triple-buffered (A(t+2) GLLs in flight across the barrier, vmcnt(4) counted),
// B double-buffered. 1 barrier per K-step.
// LDS: A bufs 3x16384 @0; B bufs 2x8192 @49152. Total 65536 B.
#define AS1C const __attribute__((address_space(1))) void*
#define AS3  __attribute__((address_space(3))) void*
#define GLL(src, dst) __builtin_amdgcn_global_load_lds((AS1C)(src), (AS3)(dst), 16, 0, 0)
#define BAR() asm volatile("s_barrier" ::: "memory")
#define VMC(N) asm volatile("s_waitcnt vmcnt(" #N ")" ::: "memory")
#define MFMA(a, b, c) __builtin_amdgcn_mfma_i32_16x16x64_i8(a, b, c, 0, 0, 0)

__global__ __launch_bounds__(256, 2) void gemm_i8_db(const int8_t* __restrict__ A8,
                                                     const int8_t* __restrict__ B8,
                                                     const int* __restrict__ wsum,
                                                     const int* __restrict__ bq,
                                                     float* __restrict__ out) {
  __shared__ uint8_t lds[65536];

  // bijective XCD swizzle: 1024 blocks, 1024 % 8 == 0
  int bid = blockIdx.x;
  int wg = (bid & 7) * 128 + (bid >> 3);
  int bm = wg >> 5;  // 32 row-tiles (256 rows)
  int bn = wg & 31;  // 32 col-tiles (128 cols)

  const int tid = threadIdx.x;
  const int lane = tid & 63;
  const int wv = tid >> 6;   // 0..3
  const int wr = wv >> 1;    // 0..1 : 128-row half
  const int wc = wv & 1;     // 0..1 : 64-col half
  const int l15 = lane & 15, hi = lane >> 4;

  // staging: unit e = is*256 + tid; r = e>>2, s = e&3; pre-swizzled col (rule #21)
  size_t aSrc[4];
  int aDstB[4];  // wave-uniform LDS base (HW adds lane*16)
#pragma unroll
  for (int is = 0; is < 4; ++is) {
    int e = is * 256 + tid;
    int r = e >> 2, s = e & 3;
    aSrc[is] = (size_t)(bm * 256 + r) * Kdim + ((s ^ (r & 3)) << 4);
    aDstB[is] = is * 4096 + wv * 1024;
  }
  size_t bSrc[2];
  int bDstB[2];
#pragma unroll
  for (int is = 0; is < 2; ++is) {
    int e = is * 256 + tid;
    int r = e >> 2, s = e & 3;
    bSrc[is] = (size_t)(bn * 128 + r) * Kdim + ((s ^ (r & 3)) << 4);
    bDstB[is] = is * 4096 + wv * 1024;
  }

#define ISSUE_A(P, t) do { \
    _Pragma("unroll") for (int is = 0; is < 4; ++is) \
      GLL(A8 + aSrc[is] + (size_t)(t) * 64, &lds[(P) * 16384 + aDstB[is]]); \
  } while (0)
#define ISSUE_B(P, t) do { \
    _Pragma("unroll") for (int is = 0; is < 2; ++is) \
      GLL(B8 + bSrc[is] + (size_t)(t) * 64, &lds[49152 + (P) * 8192 + bDstB[is]]); \
  } while (0)

  // fragment reads: row's 64B = 4 slots, stored slot = hi ^ (row&3); row&3 == l15&3.
  // A wave's b128 frag read covers 16 contiguous rows x 64B = 1 KiB -> conflict-free.
  const int sl = (hi ^ (l15 & 3)) << 4;
  const int aFrag = (wr * 128 + l15) * 64 + sl;          // + i*1024
  const int bFrag = (wc * 64 + l15) * 64 + sl;           // + j*1024

#define LDA(P, i) (*reinterpret_cast<const i32x4*>(&lds[(P) * 16384 + aFrag + (i) * 1024]))
#define LDB(P, j) (*reinterpret_cast<const i32x4*>(&lds[49152 + (P) * 8192 + bFrag + (j) * 1024]))

  i32x4 acc[8][4];
#pragma unroll
  for (int i = 0; i < 8; ++i)
#pragma unroll
    for (int j = 0; j < 4; ++j) acc[i][j] = (i32x4){0, 0, 0, 0};

  // prologue: A0, B0, A1 -> vmcnt(4) retires A0+B0, leaves A1 in flight
  ISSUE_A(0, 0);
  ISSUE_B(0, 0);
  ISSUE_A(1, 1);
  VMC(4);
  BAR();

  // Per step t: read abuf[t%3], bbuf[t&1]; issue B(t+1)->bbuf[(t+1)&1] then
  // A(t+2)->abuf[(t+2)%3] (both last read at t-1, behind the barrier).
  // vmcnt(4) retires A(t+1)+B(t+1) (6 oldest), leaves A(t+2) in flight.
#define STEP(PA, PB, PB1, PA2, t, DOB, DOA, VM4, VM0) do { \
    if (DOB) ISSUE_B(PB1, (t) + 1); \
    if (DOA) ISSUE_A(PA2, (t) + 2); \
    i32x4 a_[8], b_[4]; \
    _Pragma("unroll") for (int j = 0; j < 4; ++j) b_[j] = LDB(PB, j); \
    _Pragma("unroll") for (int i = 0; i < 8; ++i) a_[i] = LDA(PA, i); \
    __builtin_amdgcn_s_setprio(1); \
    _Pragma("unroll") for (int i = 0; i < 8; ++i) \
      _Pragma("unroll") for (int j = 0; j < 4; ++j) \
        acc[i][j] = MFMA(a_[i], b_[j], acc[i][j]); \
    __builtin_amdgcn_s_setprio(0); \
    if (VM4) VMC(4); \
    if (VM0) VMC(0); \
    BAR(); \
  } while (0)

  // buffers cycle with period 6: abuf = t%3, bbuf = t&1
  for (int it = 0; it < 10; ++it) {  // t = 0..59
    int t = it * 6;
    STEP(0, 0, 1, 2, t + 0, 1, 1, 1, 0);
    STEP(1, 1, 0, 0, t + 1, 1, 1, 1, 0);
    STEP(2, 0, 1, 1, t + 2, 1, 1, 1, 0);
    STEP(0, 1, 0, 2, t + 3, 1, 1, 1, 0);
    STEP(1, 0, 1, 0, t + 4, 1, 1, 1, 0);
    STEP(2, 1, 0, 1, t + 5, 1, 1, 1, 0);
  }
  // tail: t=60,61 full; t=62 issues B(63) only then drains; t=63 pure consume
  STEP(0, 0, 1, 2, 60, 1, 1, 1, 0);
  STEP(1, 1, 0, 0, 61, 1, 1, 1, 0);
  STEP(2, 0, 1, 0, 62, 1, 0, 0, 1);
  STEP(0, 1, 0, 0, 63, 0, 0, 0, 0);

  // epilogue: C/D layout col = lane&15, row = (lane>>4)*4 + reg
#pragma unroll
  for (int j = 0; j < 4; ++j) {
    int col = bn * 128 + wc * 64 + j * 16 + l15;
    float fb = (float)bq[col] * BSCALE;
    int ws = wsum[col];
#pragma unroll
    for (int i = 0; i < 8; ++i) {
      int rbase = bm * 256 + wr * 128 + i * 16 + hi * 4;
#pragma unroll
      for (int p = 0; p < 4; ++p)
        out[(size_t)(rbase + p) * Ndim + col] = (float)(acc[i][j][p] + ws) * OUT_SCALE + fb;
    }
  }
#undef STEP
#undef ISSUE_A
#undef ISSUE_B
#undef LDA
#undef LDB
}

// ---------------- naive fallback (only if ws_size is unexpectedly small)
__global__ void fallback_kernel(const float* __restrict__ x, const int* __restrict__ wq,
                                const int* __restrict__ bq, float* __restrict__ out) {
  int col = blockIdx.x * 16 + (threadIdx.x & 15);
  int row = blockIdx.y * 16 + (threadIdx.x >> 4);
  const float* xr = x + (size_t)row * Kdim;
  const int* wr_ = wq + (size_t)col * Kdim;
  int acc = 0;
  for (int k = 0; k < Kdim; ++k) {
    int v = (int)rintf(xr[k] / ISF + 127.0f);
    v = v < 0 ? 0 : (v > 255 ? 255 : v);
    acc += (v - 127) * wr_[k];
  }
  out[(size_t)row * Ndim + col] = (float)acc * OUT_SCALE + (float)bq[col] * BSCALE;
}

extern "C" void kernel_launch(void* const* d_in, const int* in_sizes, int n_in,
                              void* d_out, int out_size, void* d_ws, size_t ws_size,
                              hipStream_t stream) {
  const float* x = (const float*)d_in[0];
  const int* wq = (const int*)d_in[1];
  const int* bq = (const int*)d_in[2];
  float* out = (float*)d_out;

  const size_t x8_bytes = (size_t)Mdim * Kdim;  // 32 MiB
  const size_t w8_bytes = (size_t)Ndim * Kdim;  // 16 MiB
  const size_t ws_need = x8_bytes + w8_bytes + (size_t)Ndim * sizeof(int);

  if (ws_size >= ws_need) {
    int8_t* x8 = (int8_t*)d_ws;
    int8_t* w8 = x8 + x8_bytes;
    int* wsum = (int*)(w8 + w8_bytes);

    quantize_x<<<2048, 256, 0, stream>>>(x, (int*)x8, Mdim * Kdim / 4);
    convert_w<<<Ndim, 256, 0, stream>>>(wq, (int*)w8, wsum);
    gemm_i8_db<<<(Mdim / 256) * (Ndim / 128), 256, 0, stream>>>(x8, w8, wsum, bq, out);
  } else {
    dim3 grid(Ndim / 16, Mdim / 16);
    fallback_kernel<<<grid, 256, 0, stream>>>(x, wq, bq, out);
  }
}

// Round 6
// 192.005 us; speedup vs baseline: 1.2622x; 1.0596x over previous
//
#include <hip/hip_runtime.h>
#include <stdint.h>

// ---- problem constants ----
constexpr int Mdim = 8192;
constexpr int Ndim = 4096;
constexpr int Kdim = 4096;
constexpr int NT = Kdim / 128;  // 32 K-tiles of BK=128

#define ISF        ((float)(2.0 / 255.0))          // IN_SCALE
#define OUT_SCALE  ((float)(2.0 / 255.0 * 0.01))   // IN_SCALE * W_SCALE
#define BSCALE     0.01f
// IN_ZP = 127 (the +1e-12 pulls 127.5 below the .5 boundary). x_shifted in [-127,128]
// doesn't fit int8 -> compute u = x_q - 128 in [-128,127]; acc = GEMM(u,w) + rowsum_w[n].

typedef int i32x4 __attribute__((ext_vector_type(4)));

// ---------------- pre-pass 1: quantize x_float -> int8
__global__ __launch_bounds__(256) void quantize_x(const float* __restrict__ x,
                                                  int* __restrict__ x8,
                                                  int ngroups) {
  int idx = blockIdx.x * 256 + threadIdx.x;
  int stride = gridDim.x * 256;
  for (int g = idx; g < ngroups; g += stride) {
    float4 v = reinterpret_cast<const float4*>(x)[g];
    int a0 = (int)rintf(v.x / ISF + 127.0f);
    int a1 = (int)rintf(v.y / ISF + 127.0f);
    int a2 = (int)rintf(v.z / ISF + 127.0f);
    int a3 = (int)rintf(v.w / ISF + 127.0f);
    a0 = a0 < 0 ? 0 : (a0 > 255 ? 255 : a0); a0 -= 128;
    a1 = a1 < 0 ? 0 : (a1 > 255 ? 255 : a1); a1 -= 128;
    a2 = a2 < 0 ? 0 : (a2 > 255 ? 255 : a2); a2 -= 128;
    a3 = a3 < 0 ? 0 : (a3 > 255 ? 255 : a3); a3 -= 128;
    x8[g] = (a0 & 0xff) | ((a1 & 0xff) << 8) | ((a2 & 0xff) << 16) |
            (int)(((unsigned)(a3 & 0xff)) << 24);
  }
}

// ---------------- pre-pass 2: w_q int32 -> int8 packed, fused per-row sum
__global__ __launch_bounds__(256) void convert_w(const int* __restrict__ wq,
                                                 int* __restrict__ w8,
                                                 int* __restrict__ wsum) {
  int row = blockIdx.x;
  const int4* src = reinterpret_cast<const int4*>(wq + (size_t)row * Kdim);
  int* dst = w8 + (size_t)row * (Kdim / 4);
  int s = 0;
#pragma unroll
  for (int i = 0; i < 4; ++i) {
    int idx = i * 256 + threadIdx.x;
    int4 v = src[idx];
    s += v.x + v.y + v.z + v.w;
    dst[idx] = (v.x & 0xff) | ((v.y & 0xff) << 8) | ((v.z & 0xff) << 16) |
               (int)(((unsigned)(v.w & 0xff)) << 24);
  }
  __shared__ int red[256];
  red[threadIdx.x] = s;
  __syncthreads();
  for (int off = 128; off; off >>= 1) {
    if ((int)threadIdx.x < off) red[threadIdx.x] += red[threadIdx.x + off];
    __syncthreads();
  }
  if (threadIdx.x == 0) wsum[row] = red[0];
}

// ---------------- 256x128 block, BK=128, 8 waves (4x2, wave tile 64x64, acc=64 VGPR).
// Per-wave pipelined phases, ONE barrier per K-tile, A/B triple-buffered,
// counted vmcnt(6) (6 GLL/wave/tile). Frag rows 128B + round-2 swizzle (0 conflicts).
// LDS: A bufs 3x32768 @0; B bufs 3x16384 @98304. Total 147456 B.
#define AS1C const __attribute__((address_space(1))) void*
#define AS3  __attribute__((address_space(3))) void*
#define GLL(src, dst) __builtin_amdgcn_global_load_lds((AS1C)(src), (AS3)(dst), 16, 0, 0)
#define BAR() asm volatile("s_barrier" ::: "memory")
#define VMC(N) asm volatile("s_waitcnt vmcnt(" #N ")" ::: "memory")
#define MFMA(a, b, c) __builtin_amdgcn_mfma_i32_16x16x64_i8(a, b, c, 0, 0, 0)

__global__ __launch_bounds__(512, 2) void gemm_i8_pw(const int8_t* __restrict__ A8,
                                                     const int8_t* __restrict__ B8,
                                                     const int* __restrict__ wsum,
                                                     const int* __restrict__ bq,
                                                     float* __restrict__ out) {
  __shared__ uint8_t lds[147456];

  // bijective XCD swizzle: 1024 blocks, 1024 % 8 == 0
  int bid = blockIdx.x;
  int wg = (bid & 7) * 128 + (bid >> 3);
  int bm = wg >> 5;  // 32 row-tiles (256 rows)
  int bn = wg & 31;  // 32 col-tiles (128 cols)

  const int tid = threadIdx.x;
  const int lane = tid & 63;
  const int wv = tid >> 6;   // 0..7
  const int wr = wv >> 1;    // 0..3 : 64-row group
  const int wc = wv & 1;     // 0..1 : 64-col group
  const int l15 = lane & 15, hi = lane >> 4;

  // staging: A tile 32KB (4 GLL/wave), B tile 16KB (2 GLL/wave); unit e covers 16B,
  // r = e>>3 (8 slots per 128B row), s = e&7; pre-swizzled source col (rule #21).
  size_t aSrc[4];
#pragma unroll
  for (int is = 0; is < 4; ++is) {
    int e = is * 512 + tid;
    int r = e >> 3, s = e & 7;
    aSrc[is] = (size_t)(bm * 256 + r) * Kdim + ((s ^ (r & 7)) << 4);
  }
  size_t bSrc[2];
#pragma unroll
  for (int is = 0; is < 2; ++is) {
    int e = is * 512 + tid;
    int r = e >> 3, s = e & 7;
    bSrc[is] = (size_t)(bn * 128 + r) * Kdim + ((s ^ (r & 7)) << 4);
  }
  const int ldsw = wv * 1024;

#define ISSUE_A(P, t) do { \
    _Pragma("unroll") for (int is = 0; is < 4; ++is) \
      GLL(A8 + aSrc[is] + (size_t)(t) * 128, &lds[(P) * 32768 + is * 8192 + ldsw]); \
  } while (0)
#define ISSUE_B(P, t) do { \
    _Pragma("unroll") for (int is = 0; is < 2; ++is) \
      GLL(B8 + bSrc[is] + (size_t)(t) * 128, &lds[98304 + (P) * 16384 + is * 8192 + ldsw]); \
  } while (0)

  // fragment addressing (round-2 verified, 0 conflicts): slot = (ks*4+hi) ^ (l15&7)
  const int aRow = (wr * 64 + l15) * 128;
  const int bRow = (wc * 64 + l15) * 128;
  const int sl0 = (hi ^ (l15 & 7)) << 4;
  const int sl1 = ((4 + hi) ^ (l15 & 7)) << 4;

#define LDA(P, i, ks) (*reinterpret_cast<const i32x4*>( \
    &lds[(P) * 32768 + aRow + (i) * 2048 + ((ks) ? sl1 : sl0)]))
#define LDB(P, j, ks) (*reinterpret_cast<const i32x4*>( \
    &lds[98304 + (P) * 16384 + bRow + (j) * 2048 + ((ks) ? sl1 : sl0)]))

  i32x4 acc[4][4];
#pragma unroll
  for (int i = 0; i < 4; ++i)
#pragma unroll
    for (int j = 0; j < 4; ++j) acc[i][j] = (i32x4){0, 0, 0, 0};

  // frag register sets (a0/B0 reused across tiles via cross-tile reads)
  i32x4 a0[4], a1[4], B0[4], B1[4];

  // prologue: stage tiles 0,1; vmcnt(6) retires tile0's 6, leaves tile1's in flight
  ISSUE_A(0, 0); ISSUE_B(0, 0);
  ISSUE_A(1, 1); ISSUE_B(1, 1);
  VMC(6);
  BAR();
#pragma unroll
  for (int i = 0; i < 4; ++i) a0[i] = LDA(0, i, 0);
  B0[0] = LDB(0, 0, 0); B0[1] = LDB(0, 1, 0);

  // Per tile t (buf TB=t%3, next TN=(t+1)%3, stage TG=(t+2)%3), 4 phases x 8 MFMA.
  // Each phase issues the NEXT phase's ds_reads before its MFMA cluster (compiler
  // emits counted lgkm waits -> reads hide under the previous MFMA cluster).
  // P3 issues GLLs for t+2 (into buf read at t-1, safe: those reads drained before
  // t-1's barrier, GLL issued after it). vmcnt(6)+barrier before P4's cross-tile
  // reads of buf TN (all of t+1 landed). Never drains to 0 in steady state.
#define TILE(TB, TN, TG, t, DOG, VM6, VM0, CROSS, DOBAR) do { \
    /* P1 */ \
    B0[2] = LDB(TB, 2, 0); B0[3] = LDB(TB, 3, 0); \
    B1[0] = LDB(TB, 0, 1); B1[1] = LDB(TB, 1, 1); \
    __builtin_amdgcn_s_setprio(1); \
    _Pragma("unroll") for (int i = 0; i < 4; ++i) { \
      acc[i][0] = MFMA(a0[i], B0[0], acc[i][0]); \
      acc[i][1] = MFMA(a0[i], B0[1], acc[i][1]); } \
    __builtin_amdgcn_s_setprio(0); \
    /* P2 */ \
    _Pragma("unroll") for (int i = 0; i < 4; ++i) a1[i] = LDA(TB, i, 1); \
    B1[2] = LDB(TB, 2, 1); B1[3] = LDB(TB, 3, 1); \
    __builtin_amdgcn_s_setprio(1); \
    _Pragma("unroll") for (int i = 0; i < 4; ++i) { \
      acc[i][2] = MFMA(a0[i], B0[2], acc[i][2]); \
      acc[i][3] = MFMA(a0[i], B0[3], acc[i][3]); } \
    __builtin_amdgcn_s_setprio(0); \
    /* P3 */ \
    if (DOG) { ISSUE_A(TG, (t) + 2); ISSUE_B(TG, (t) + 2); } \
    __builtin_amdgcn_s_setprio(1); \
    _Pragma("unroll") for (int i = 0; i < 4; ++i) { \
      acc[i][0] = MFMA(a1[i], B1[0], acc[i][0]); \
      acc[i][1] = MFMA(a1[i], B1[1], acc[i][1]); } \
    __builtin_amdgcn_s_setprio(0); \
    if (VM6) VMC(6); \
    if (VM0) VMC(0); \
    if (DOBAR) BAR(); \
    /* P4 (+ cross-tile reads for next tile's P1, reusing dead a0/B0 regs) */ \
    if (CROSS) { \
      _Pragma("unroll") for (int i = 0; i < 4; ++i) a0[i] = LDA(TN, i, 0); \
      B0[0] = LDB(TN, 0, 0); B0[1] = LDB(TN, 1, 0); } \
    __builtin_amdgcn_s_setprio(1); \
    _Pragma("unroll") for (int i = 0; i < 4; ++i) { \
      acc[i][2] = MFMA(a1[i], B1[2], acc[i][2]); \
      acc[i][3] = MFMA(a1[i], B1[3], acc[i][3]); } \
    __builtin_amdgcn_s_setprio(0); \
  } while (0)

  for (int it = 0; it < NT / 3 - 1; ++it) {  // 9 iters: t = 0..26
    int t = it * 3;
    TILE(0, 1, 2, t + 0, 1, 1, 0, 1, 1);
    TILE(1, 2, 0, t + 1, 1, 1, 0, 1, 1);
    TILE(2, 0, 1, t + 2, 1, 1, 0, 1, 1);
  }
  // t=27..29 full steady; t=30 stages nothing, drains t31; t=31 pure consume
  TILE(0, 1, 2, 27, 1, 1, 0, 1, 1);
  TILE(1, 2, 0, 28, 1, 1, 0, 1, 1);
  TILE(2, 0, 1, 29, 1, 1, 0, 1, 1);
  TILE(0, 1, 2, 30, 0, 0, 1, 1, 1);
  TILE(1, 2, 0, 31, 0, 0, 0, 0, 0);

  // epilogue: C/D layout col = lane&15, row = (lane>>4)*4 + reg
#pragma unroll
  for (int j = 0; j < 4; ++j) {
    int col = bn * 128 + wc * 64 + j * 16 + l15;
    float fb = (float)bq[col] * BSCALE;
    int ws = wsum[col];
#pragma unroll
    for (int i = 0; i < 4; ++i) {
      int rbase = bm * 256 + wr * 64 + i * 16 + hi * 4;
#pragma unroll
      for (int p = 0; p < 4; ++p)
        out[(size_t)(rbase + p) * Ndim + col] = (float)(acc[i][j][p] + ws) * OUT_SCALE + fb;
    }
  }
#undef TILE
#undef ISSUE_A
#undef ISSUE_B
#undef LDA
#undef LDB
}

// ---------------- naive fallback (only if ws_size is unexpectedly small)
__global__ void fallback_kernel(const float* __restrict__ x, const int* __restrict__ wq,
                                const int* __restrict__ bq, float* __restrict__ out) {
  int col = blockIdx.x * 16 + (threadIdx.x & 15);
  int row = blockIdx.y * 16 + (threadIdx.x >> 4);
  const float* xr = x + (size_t)row * Kdim;
  const int* wr_ = wq + (size_t)col * Kdim;
  int acc = 0;
  for (int k = 0; k < Kdim; ++k) {
    int v = (int)rintf(xr[k] / ISF + 127.0f);
    v = v < 0 ? 0 : (v > 255 ? 255 : v);
    acc += (v - 127) * wr_[k];
  }
  out[(size_t)row * Ndim + col] = (float)acc * OUT_SCALE + (float)bq[col] * BSCALE;
}

extern "C" void kernel_launch(void* const* d_in, const int* in_sizes, int n_in,
                              void* d_out, int out_size, void* d_ws, size_t ws_size,
                              hipStream_t stream) {
  const float* x = (const float*)d_in[0];
  const int* wq = (const int*)d_in[1];
  const int* bq = (const int*)d_in[2];
  float* out = (float*)d_out;

  const size_t x8_bytes = (size_t)Mdim * Kdim;  // 32 MiB
  const size_t w8_bytes = (size_t)Ndim * Kdim;  // 16 MiB
  const size_t ws_need = x8_bytes + w8_bytes + (size_t)Ndim * sizeof(int);

  if (ws_size >= ws_need) {
    int8_t* x8 = (int8_t*)d_ws;
    int8_t* w8 = x8 + x8_bytes;
    int* wsum = (int*)(w8 + w8_bytes);

    quantize_x<<<2048, 256, 0, stream>>>(x, (int*)x8, Mdim * Kdim / 4);
    convert_w<<<Ndim, 256, 0, stream>>>(wq, (int*)w8, wsum);
    gemm_i8_pw<<<(Mdim / 256) * (Ndim / 128), 512, 0, stream>>>(x8, w8, wsum, bq, out);
  } else {
    dim3 grid(Ndim / 16, Mdim / 16);
    fallback_kernel<<<grid, 256, 0, stream>>>(x, wq, bq, out);
  }
}

// Round 8
// 181.977 us; speedup vs baseline: 1.3317x; 1.0551x over previous
//
#include <hip/hip_runtime.h>
#include <stdint.h>

// ---- problem constants ----
constexpr int Mdim = 8192;
constexpr int Ndim = 4096;
constexpr int Kdim = 4096;
constexpr int NT = Kdim / 128;  // 32 K-tiles of BK=128

#define ISF        ((float)(2.0 / 255.0))          // IN_SCALE
#define OUT_SCALE  ((float)(2.0 / 255.0 * 0.01))   // IN_SCALE * W_SCALE
#define BSCALE     0.01f
// IN_ZP = 127 (the +1e-12 pulls 127.5 below the .5 boundary). x_shifted in [-127,128]
// doesn't fit int8 -> compute u = x_q - 128 in [-128,127]; acc = GEMM(u,w) + rowsum_w[n].

typedef int i32x4 __attribute__((ext_vector_type(4)));

// ---------------- pre-pass 1: quantize x_float -> int8
__global__ __launch_bounds__(256) void quantize_x(const float* __restrict__ x,
                                                  int* __restrict__ x8,
                                                  int ngroups) {
  int idx = blockIdx.x * 256 + threadIdx.x;
  int stride = gridDim.x * 256;
  for (int g = idx; g < ngroups; g += stride) {
    float4 v = reinterpret_cast<const float4*>(x)[g];
    int a0 = (int)rintf(v.x / ISF + 127.0f);
    int a1 = (int)rintf(v.y / ISF + 127.0f);
    int a2 = (int)rintf(v.z / ISF + 127.0f);
    int a3 = (int)rintf(v.w / ISF + 127.0f);
    a0 = a0 < 0 ? 0 : (a0 > 255 ? 255 : a0); a0 -= 128;
    a1 = a1 < 0 ? 0 : (a1 > 255 ? 255 : a1); a1 -= 128;
    a2 = a2 < 0 ? 0 : (a2 > 255 ? 255 : a2); a2 -= 128;
    a3 = a3 < 0 ? 0 : (a3 > 255 ? 255 : a3); a3 -= 128;
    x8[g] = (a0 & 0xff) | ((a1 & 0xff) << 8) | ((a2 & 0xff) << 16) |
            (int)(((unsigned)(a3 & 0xff)) << 24);
  }
}

// ---------------- pre-pass 2: w_q int32 -> int8 packed, fused per-row sum
__global__ __launch_bounds__(256) void convert_w(const int* __restrict__ wq,
                                                 int* __restrict__ w8,
                                                 int* __restrict__ wsum) {
  int row = blockIdx.x;
  const int4* src = reinterpret_cast<const int4*>(wq + (size_t)row * Kdim);
  int* dst = w8 + (size_t)row * (Kdim / 4);
  int s = 0;
#pragma unroll
  for (int i = 0; i < 4; ++i) {
    int idx = i * 256 + threadIdx.x;
    int4 v = src[idx];
    s += v.x + v.y + v.z + v.w;
    dst[idx] = (v.x & 0xff) | ((v.y & 0xff) << 8) | ((v.z & 0xff) << 16) |
               (int)(((unsigned)(v.w & 0xff)) << 24);
  }
  __shared__ int red[256];
  red[threadIdx.x] = s;
  __syncthreads();
  for (int off = 128; off; off >>= 1) {
    if ((int)threadIdx.x < off) red[threadIdx.x] += red[threadIdx.x + off];
    __syncthreads();
  }
  if (threadIdx.x == 0) wsum[row] = red[0];
}

// ---------------- 256x256, BK=128, 8 waves. 4 phases/K-tile, balanced ds_reads
// 8/4/8/4 (C-quadrant per phase), reads->BAR->lgkmcnt(0)->sched_barrier(0)->
// setprio->16 MFMA->setprio->BAR. A TRIPLE-buffered, B double. Counted vmcnt(4).
// LDS: A bufs 3x32768 @0; B bufs 2x32768 @98304. Total 163840 B (= gfx950 max).
#define AS1C const __attribute__((address_space(1))) void*
#define AS3  __attribute__((address_space(3))) void*
#define GLL(src, dst) __builtin_amdgcn_global_load_lds((AS1C)(src), (AS3)(dst), 16, 0, 0)
#define BAR() asm volatile("s_barrier" ::: "memory")
#define LGK0() do { asm volatile("s_waitcnt lgkmcnt(0)" ::: "memory"); \
                    __builtin_amdgcn_sched_barrier(0); } while (0)
#define VMC(N) asm volatile("s_waitcnt vmcnt(" #N ")" ::: "memory")
#define MFMA(a, b, c) __builtin_amdgcn_mfma_i32_16x16x64_i8(a, b, c, 0, 0, 0)
#define BBASE 98304

__global__ __launch_bounds__(512, 2) void gemm_i8_q(const int8_t* __restrict__ A8,
                                                    const int8_t* __restrict__ B8,
                                                    const int* __restrict__ wsum,
                                                    const int* __restrict__ bq,
                                                    float* __restrict__ out) {
  __shared__ uint8_t lds[163840];

  // bijective XCD swizzle: 512 blocks, 512 % 8 == 0
  int bid = blockIdx.x;
  int wg = (bid & 7) * 64 + (bid >> 3);
  int bm = wg >> 4;  // 32 row-tiles
  int bn = wg & 15;  // 16 col-tiles

  const int tid = threadIdx.x;
  const int lane = tid & 63;
  const int wv = tid >> 6;   // 0..7
  const int wr = wv >> 2;    // 0..1 : 128-row half of C
  const int wc = wv & 3;     // 0..3 : 64-col quarter of C
  const int l15 = lane & 15, hi = lane >> 4;

  // staging source (per lane): row-chunk r3, slot s3, pre-swizzled col (rule #21)
  const int r3 = lane >> 3, s3 = lane & 7;
  const int swcol = (s3 ^ r3) << 4;
  const size_t aoff = (size_t)(bm * 256 + wv * 8 + r3) * Kdim + swcol;
  const size_t boff = (size_t)(bn * 256 + wv * 8 + r3) * Kdim + swcol;
  const int ldsw = wv * 1024;

#define ISSUE_A(P, t, half) do { \
    GLL(A8 + aoff + (size_t)(t) * 128 + (size_t)((half) * 128) * Kdim, \
        &lds[(P) * 32768 + (half) * 16384 + ldsw]); \
    GLL(A8 + aoff + (size_t)(t) * 128 + (size_t)((half) * 128 + 64) * Kdim, \
        &lds[(P) * 32768 + (half) * 16384 + 8192 + ldsw]); \
  } while (0)
#define ISSUE_B(P, t, half) do { \
    GLL(B8 + boff + (size_t)(t) * 128 + (size_t)((half) * 128) * Kdim, \
        &lds[BBASE + (P) * 32768 + (half) * 16384 + ldsw]); \
    GLL(B8 + boff + (size_t)(t) * 128 + (size_t)((half) * 128 + 64) * Kdim, \
        &lds[BBASE + (P) * 32768 + (half) * 16384 + 8192 + ldsw]); \
  } while (0)

  // fragment addressing (round-2 verified, 0 conflicts): slot = (ks*4+hi) ^ (l15&7)
  const int aRow = (wr * 128 + l15) * 128;
  const int bRow = (wc * 64 + l15) * 128;
  const int sl0 = (hi ^ (l15 & 7)) << 4;
  const int sl1 = ((4 + hi) ^ (l15 & 7)) << 4;

#define LDA(P, i, ks) (*reinterpret_cast<const i32x4*>( \
    &lds[(P) * 32768 + aRow + (i) * 2048 + ((ks) ? sl1 : sl0)]))
#define LDB(P, j, ks) (*reinterpret_cast<const i32x4*>( \
    &lds[BBASE + (P) * 32768 + bRow + (j) * 2048 + ((ks) ? sl1 : sl0)]))

  i32x4 acc[8][4];
#pragma unroll
  for (int i = 0; i < 8; ++i)
#pragma unroll
    for (int j = 0; j < 4; ++j) acc[i][j] = (i32x4){0, 0, 0, 0};

  // prologue: A(0),B(0) (8 GLL) + A(1) (4 GLL); vmcnt(4) retires A0+B0.
  ISSUE_A(0, 0, 0); ISSUE_A(0, 0, 1);
  ISSUE_B(0, 0, 0); ISSUE_B(0, 0, 1);
  ISSUE_A(1, 1, 0); ISSUE_A(1, 1, 1);
  VMC(4);
  BAR();

  // Tile t: A buf TA=t%3 (read all 4 phases), B buf TB=t&1 (P1: ks0, P3: ks1).
  // Stage B(t+1)->TB^1 at P1/P2 (last read t-1 P3, drained behind 2 barriers).
  // Stage A(t+2)->TA2=(t+2)%3 at P3/P4 (last read t-1 P4, drained). vmcnt(4) at
  // P4 retires A(t+1)+B(t+1) (8 oldest), leaves A(t+2) in flight — never drains
  // to 0 in steady state. Phases (16 MFMA each, C-quadrants):
  //  P1: rd B.ks0(4)+a03.ks0(4) | P2: rd a47.ks0(4) | P3: rd B.ks1(4)+a03.ks1(4)
  //  P4: rd a47.ks1(4)
#define TILE(TA, TB, TA2, t, DOB, DOA, VM4, VM0) do { \
    i32x4 a_[4], B0[4], B1[4]; \
    /* P1 */ \
    if (DOB) ISSUE_B((TB) ^ 1, (t) + 1, 0); \
    B0[0] = LDB(TB, 0, 0); B0[1] = LDB(TB, 1, 0); B0[2] = LDB(TB, 2, 0); B0[3] = LDB(TB, 3, 0); \
    a_[0] = LDA(TA, 0, 0); a_[1] = LDA(TA, 1, 0); a_[2] = LDA(TA, 2, 0); a_[3] = LDA(TA, 3, 0); \
    BAR(); LGK0(); __builtin_amdgcn_s_setprio(1); \
    _Pragma("unroll") for (int i = 0; i < 4; ++i) \
      _Pragma("unroll") for (int j = 0; j < 4; ++j) \
        acc[i][j] = MFMA(a_[i], B0[j], acc[i][j]); \
    __builtin_amdgcn_s_setprio(0); BAR(); \
    /* P2 */ \
    if (DOB) ISSUE_B((TB) ^ 1, (t) + 1, 1); \
    a_[0] = LDA(TA, 4, 0); a_[1] = LDA(TA, 5, 0); a_[2] = LDA(TA, 6, 0); a_[3] = LDA(TA, 7, 0); \
    BAR(); LGK0(); __builtin_amdgcn_s_setprio(1); \
    _Pragma("unroll") for (int i = 0; i < 4; ++i) \
      _Pragma("unroll") for (int j = 0; j < 4; ++j) \
        acc[i + 4][j] = MFMA(a_[i], B0[j], acc[i + 4][j]); \
    __builtin_amdgcn_s_setprio(0); BAR(); \
    /* P3 */ \
    if (DOA) ISSUE_A(TA2, (t) + 2, 0); \
    B1[0] = LDB(TB, 0, 1); B1[1] = LDB(TB, 1, 1); B1[2] = LDB(TB, 2, 1); B1[3] = LDB(TB, 3, 1); \
    a_[0] = LDA(TA, 0, 1); a_[1] = LDA(TA, 1, 1); a_[2] = LDA(TA, 2, 1); a_[3] = LDA(TA, 3, 1); \
    BAR(); LGK0(); __builtin_amdgcn_s_setprio(1); \
    _Pragma("unroll") for (int i = 0; i < 4; ++i) \
      _Pragma("unroll") for (int j = 0; j < 4; ++j) \
        acc[i][j] = MFMA(a_[i], B1[j], acc[i][j]); \
    __builtin_amdgcn_s_setprio(0); BAR(); \
    /* P4 */ \
    if (DOA) ISSUE_A(TA2, (t) + 2, 1); \
    a_[0] = LDA(TA, 4, 1); a_[1] = LDA(TA, 5, 1); a_[2] = LDA(TA, 6, 1); a_[3] = LDA(TA, 7, 1); \
    BAR(); LGK0(); __builtin_amdgcn_s_setprio(1); \
    _Pragma("unroll") for (int i = 0; i < 4; ++i) \
      _Pragma("unroll") for (int j = 0; j < 4; ++j) \
        acc[i + 4][j] = MFMA(a_[i], B1[j], acc[i + 4][j]); \
    __builtin_amdgcn_s_setprio(0); \
    if (VM4) VMC(4); \
    if (VM0) VMC(0); \
    BAR(); \
  } while (0)

  for (int it = 0; it < 5; ++it) {  // 30 tiles: t = 0..29
    int t = it * 6;
    TILE(0, 0, 2, t + 0, 1, 1, 1, 0);
    TILE(1, 1, 0, t + 1, 1, 1, 1, 0);
    TILE(2, 0, 1, t + 2, 1, 1, 1, 0);
    TILE(0, 1, 2, t + 3, 1, 1, 1, 0);
    TILE(1, 0, 0, t + 4, 1, 1, 1, 0);
    TILE(2, 1, 1, t + 5, 1, 1, 1, 0);
  }
  // t=30 (TA=0,TB=0): stage B(31) only; drain all before tile31. t=31 (TA=1,TB=1).
  TILE(0, 0, 2, 30, 1, 0, 0, 1);
  TILE(1, 1, 0, 31, 0, 0, 0, 0);

  // epilogue: C/D layout col = lane&15, row = (lane>>4)*4 + reg
#pragma unroll
  for (int j = 0; j < 4; ++j) {
    int col = bn * 256 + wc * 64 + j * 16 + l15;
    float fb = (float)bq[col] * BSCALE;
    int ws = wsum[col];
#pragma unroll
    for (int i = 0; i < 8; ++i) {
      int rbase = bm * 256 + wr * 128 + i * 16 + hi * 4;
#pragma unroll
      for (int p = 0; p < 4; ++p)
        out[(size_t)(rbase + p) * Ndim + col] = (float)(acc[i][j][p] + ws) * OUT_SCALE + fb;
    }
  }
#undef TILE
#undef ISSUE_A
#undef ISSUE_B
#undef LDA
#undef LDB
}

// ---------------- naive fallback (only if ws_size is unexpectedly small)
__global__ void fallback_kernel(const float* __restrict__ x, const int* __restrict__ wq,
                                const int* __restrict__ bq, float* __restrict__ out) {
  int col = blockIdx.x * 16 + (threadIdx.x & 15);
  int row = blockIdx.y * 16 + (threadIdx.x >> 4);
  const float* xr = x + (size_t)row * Kdim;
  const int* wr_ = wq + (size_t)col * Kdim;
  int acc = 0;
  for (int k = 0; k < Kdim; ++k) {
    int v = (int)rintf(xr[k] / ISF + 127.0f);
    v = v < 0 ? 0 : (v > 255 ? 255 : v);
    acc += (v - 127) * wr_[k];
  }
  out[(size_t)row * Ndim + col] = (float)acc * OUT_SCALE + (float)bq[col] * BSCALE;
}

extern "C" void kernel_launch(void* const* d_in, const int* in_sizes, int n_in,
                              void* d_out, int out_size, void* d_ws, size_t ws_size,
                              hipStream_t stream) {
  const float* x = (const float*)d_in[0];
  const int* wq = (const int*)d_in[1];
  const int* bq = (const int*)d_in[2];
  float* out = (float*)d_out;

  const size_t x8_bytes = (size_t)Mdim * Kdim;  // 32 MiB
  const size_t w8_bytes = (size_t)Ndim * Kdim;  // 16 MiB
  const size_t ws_need = x8_bytes + w8_bytes + (size_t)Ndim * sizeof(int);

  if (ws_size >= ws_need) {
    int8_t* x8 = (int8_t*)d_ws;
    int8_t* w8 = x8 + x8_bytes;
    int* wsum = (int*)(w8 + w8_bytes);

    quantize_x<<<2048, 256, 0, stream>>>(x, (int*)x8, Mdim * Kdim / 4);
    convert_w<<<Ndim, 256, 0, stream>>>(wq, (int*)w8, wsum);
    gemm_i8_q<<<(Mdim / 256) * (Ndim / 256), 512, 0, stream>>>(x8, w8, wsum, bq, out);
  } else {
    dim3 grid(Ndim / 16, Mdim / 16);
    fallback_kernel<<<grid, 256, 0, stream>>>(x, wq, bq, out);
  }
}

// Round 9
// 180.052 us; speedup vs baseline: 1.3460x; 1.0107x over previous
//
#include <hip/hip_runtime.h>
#include <stdint.h>

// ---- problem constants ----
constexpr int Mdim = 8192;
constexpr int Ndim = 4096;
constexpr int Kdim = 4096;
constexpr int NT = Kdim / 128;  // 32 K-tiles of BK=128

#define ISF        ((float)(2.0 / 255.0))          // IN_SCALE
#define OUT_SCALE  ((float)(2.0 / 255.0 * 0.01))   // IN_SCALE * W_SCALE
#define BSCALE     0.01f
// IN_ZP = 127 (the +1e-12 pulls 127.5 below the .5 boundary). x_shifted in [-127,128]
// doesn't fit int8 -> compute u = x_q - 128 in [-128,127]; acc = GEMM(u,w) + rowsum_w[n].

typedef int i32x4 __attribute__((ext_vector_type(4)));

// ---------------- pre-pass 1: quantize x_float -> int8
__global__ __launch_bounds__(256) void quantize_x(const float* __restrict__ x,
                                                  int* __restrict__ x8,
                                                  int ngroups) {
  int idx = blockIdx.x * 256 + threadIdx.x;
  int stride = gridDim.x * 256;
  for (int g = idx; g < ngroups; g += stride) {
    float4 v = reinterpret_cast<const float4*>(x)[g];
    int a0 = (int)rintf(v.x / ISF + 127.0f);
    int a1 = (int)rintf(v.y / ISF + 127.0f);
    int a2 = (int)rintf(v.z / ISF + 127.0f);
    int a3 = (int)rintf(v.w / ISF + 127.0f);
    a0 = a0 < 0 ? 0 : (a0 > 255 ? 255 : a0); a0 -= 128;
    a1 = a1 < 0 ? 0 : (a1 > 255 ? 255 : a1); a1 -= 128;
    a2 = a2 < 0 ? 0 : (a2 > 255 ? 255 : a2); a2 -= 128;
    a3 = a3 < 0 ? 0 : (a3 > 255 ? 255 : a3); a3 -= 128;
    x8[g] = (a0 & 0xff) | ((a1 & 0xff) << 8) | ((a2 & 0xff) << 16) |
            (int)(((unsigned)(a3 & 0xff)) << 24);
  }
}

// ---------------- pre-pass 2: w_q int32 -> int8 packed, fused per-row sum
__global__ __launch_bounds__(256) void convert_w(const int* __restrict__ wq,
                                                 int* __restrict__ w8,
                                                 int* __restrict__ wsum) {
  int row = blockIdx.x;
  const int4* src = reinterpret_cast<const int4*>(wq + (size_t)row * Kdim);
  int* dst = w8 + (size_t)row * (Kdim / 4);
  int s = 0;
#pragma unroll
  for (int i = 0; i < 4; ++i) {
    int idx = i * 256 + threadIdx.x;
    int4 v = src[idx];
    s += v.x + v.y + v.z + v.w;
    dst[idx] = (v.x & 0xff) | ((v.y & 0xff) << 8) | ((v.z & 0xff) << 16) |
               (int)(((unsigned)(v.w & 0xff)) << 24);
  }
  __shared__ int red[256];
  red[threadIdx.x] = s;
  __syncthreads();
  for (int off = 128; off; off >>= 1) {
    if ((int)threadIdx.x < off) red[threadIdx.x] += red[threadIdx.x + off];
    __syncthreads();
  }
  if (threadIdx.x == 0) wsum[row] = red[0];
}

// ---------------- 256x256, BK=128, 8 waves. ONE barrier per K-tile; intra-tile
// pipeline via counted lgkmcnt (DS retires in-order): read-chunks interleaved with
// 4x16-MFMA groups, sched_barrier(0) walls pin order (rule #18). A triple-buffered,
// B double. Counted vmcnt(4). LDS: A 3x32768 @0; B 2x32768 @98304 = 163840 B.
#define AS1C const __attribute__((address_space(1))) void*
#define AS3  __attribute__((address_space(3))) void*
#define GLL(src, dst) __builtin_amdgcn_global_load_lds((AS1C)(src), (AS3)(dst), 16, 0, 0)
#define BAR() asm volatile("s_barrier" ::: "memory")
#define SB0() __builtin_amdgcn_sched_barrier(0)
#define LGK(N) do { asm volatile("s_waitcnt lgkmcnt(" #N ")" ::: "memory"); SB0(); } while (0)
#define VMC(N) asm volatile("s_waitcnt vmcnt(" #N ")" ::: "memory")
#define MFMA(a, b, c) __builtin_amdgcn_mfma_i32_16x16x64_i8(a, b, c, 0, 0, 0)
#define BBASE 98304

__global__ __launch_bounds__(512, 2) void gemm_i8_pipe(const int8_t* __restrict__ A8,
                                                       const int8_t* __restrict__ B8,
                                                       const int* __restrict__ wsum,
                                                       const int* __restrict__ bq,
                                                       float* __restrict__ out) {
  __shared__ uint8_t lds[163840];

  // bijective XCD swizzle: 512 blocks, 512 % 8 == 0
  int bid = blockIdx.x;
  int wg = (bid & 7) * 64 + (bid >> 3);
  int bm = wg >> 4;  // 32 row-tiles
  int bn = wg & 15;  // 16 col-tiles

  const int tid = threadIdx.x;
  const int lane = tid & 63;
  const int wv = tid >> 6;   // 0..7
  const int wr = wv >> 2;    // 0..1 : 128-row half of C
  const int wc = wv & 3;     // 0..3 : 64-col quarter of C
  const int l15 = lane & 15, hi = lane >> 4;

  // staging source (per lane): row-chunk r3, slot s3, pre-swizzled col (rule #21)
  const int r3 = lane >> 3, s3 = lane & 7;
  const int swcol = (s3 ^ r3) << 4;
  const size_t aoff = (size_t)(bm * 256 + wv * 8 + r3) * Kdim + swcol;
  const size_t boff = (size_t)(bn * 256 + wv * 8 + r3) * Kdim + swcol;
  const int ldsw = wv * 1024;

#define ISSUE_A(P, t, half) do { \
    GLL(A8 + aoff + (size_t)(t) * 128 + (size_t)((half) * 128) * Kdim, \
        &lds[(P) * 32768 + (half) * 16384 + ldsw]); \
    GLL(A8 + aoff + (size_t)(t) * 128 + (size_t)((half) * 128 + 64) * Kdim, \
        &lds[(P) * 32768 + (half) * 16384 + 8192 + ldsw]); \
  } while (0)
#define ISSUE_B(P, t, half) do { \
    GLL(B8 + boff + (size_t)(t) * 128 + (size_t)((half) * 128) * Kdim, \
        &lds[BBASE + (P) * 32768 + (half) * 16384 + ldsw]); \
    GLL(B8 + boff + (size_t)(t) * 128 + (size_t)((half) * 128 + 64) * Kdim, \
        &lds[BBASE + (P) * 32768 + (half) * 16384 + 8192 + ldsw]); \
  } while (0)

  // fragment addressing (round-2 verified, 0 conflicts): slot = (ks*4+hi) ^ (l15&7)
  const int aRow = (wr * 128 + l15) * 128;
  const int bRow = (wc * 64 + l15) * 128;
  const int sl0 = (hi ^ (l15 & 7)) << 4;
  const int sl1 = ((4 + hi) ^ (l15 & 7)) << 4;

#define LDA(P, i, ks) (*reinterpret_cast<const i32x4*>( \
    &lds[(P) * 32768 + aRow + (i) * 2048 + ((ks) ? sl1 : sl0)]))
#define LDB(P, j, ks) (*reinterpret_cast<const i32x4*>( \
    &lds[BBASE + (P) * 32768 + bRow + (j) * 2048 + ((ks) ? sl1 : sl0)]))

  i32x4 acc[8][4];
#pragma unroll
  for (int i = 0; i < 8; ++i)
#pragma unroll
    for (int j = 0; j < 4; ++j) acc[i][j] = (i32x4){0, 0, 0, 0};

#define GRP(AV, BV, IOFF) do { \
    _Pragma("unroll") for (int i = 0; i < 4; ++i) \
      _Pragma("unroll") for (int j = 0; j < 4; ++j) \
        acc[i + (IOFF)][j] = MFMA(AV[i], BV[j], acc[i + (IOFF)][j]); \
  } while (0)

  // prologue: A(0),B(0) (8 GLL) + A(1) (4 GLL); vmcnt(4) retires A0+B0.
  ISSUE_A(0, 0, 0); ISSUE_A(0, 0, 1);
  ISSUE_B(0, 0, 0); ISSUE_B(0, 0, 1);
  ISSUE_A(1, 1, 0); ISSUE_A(1, 1, 1);
  VMC(4);
  BAR();

  // Tile t: A buf TA=t%3, B buf TB=t&1. GLLs first: B(t+1)->TB^1 (last read t-1,
  // drained by every wave's lgkm(0) before t-1's closing barrier), A(t+2)->TA2
  // (last read t-1, same). Then 24 ds_reads in chunks, 4 MFMA groups gated by
  // counted lgkm (DS in-order). vmcnt(4) at end retires A(t+1)+B(t+1), leaves
  // A(t+2) in flight — never drains to 0 in steady state. ONE barrier per tile.
#define TILE(TA, TB, TA2, t, DOB, DOA, VM4, VM0) do { \
    if (DOB) { ISSUE_B((TB) ^ 1, (t) + 1, 0); ISSUE_B((TB) ^ 1, (t) + 1, 1); } \
    if (DOA) { ISSUE_A(TA2, (t) + 2, 0); ISSUE_A(TA2, (t) + 2, 1); } \
    i32x4 B0[4], B1[4], a0[4], a1[4], a2[4], a3[4]; \
    /* chunk1: B0 + a03.ks0 (8 reads) */ \
    B0[0] = LDB(TB, 0, 0); B0[1] = LDB(TB, 1, 0); B0[2] = LDB(TB, 2, 0); B0[3] = LDB(TB, 3, 0); \
    a0[0] = LDA(TA, 0, 0); a0[1] = LDA(TA, 1, 0); a0[2] = LDA(TA, 2, 0); a0[3] = LDA(TA, 3, 0); \
    SB0(); \
    /* chunk2: a47.ks0 + B1 (8 reads) */ \
    a1[0] = LDA(TA, 4, 0); a1[1] = LDA(TA, 5, 0); a1[2] = LDA(TA, 6, 0); a1[3] = LDA(TA, 7, 0); \
    B1[0] = LDB(TB, 0, 1); B1[1] = LDB(TB, 1, 1); B1[2] = LDB(TB, 2, 1); B1[3] = LDB(TB, 3, 1); \
    SB0(); \
    LGK(8);  /* chunk1 done; chunk2 (8) in flight */ \
    __builtin_amdgcn_s_setprio(1); \
    GRP(a0, B0, 0); \
    __builtin_amdgcn_s_setprio(0); SB0(); \
    /* chunk3: a03.ks1 (4 reads) -> 12 in flight */ \
    a2[0] = LDA(TA, 0, 1); a2[1] = LDA(TA, 1, 1); a2[2] = LDA(TA, 2, 1); a2[3] = LDA(TA, 3, 1); \
    SB0(); \
    LGK(4);  /* chunk2 done; chunk3 (4) in flight */ \
    __builtin_amdgcn_s_setprio(1); \
    GRP(a1, B0, 4); \
    __builtin_amdgcn_s_setprio(0); SB0(); \
    /* chunk4: a47.ks1 (4 reads) -> 8 in flight */ \
    a3[0] = LDA(TA, 4, 1); a3[1] = LDA(TA, 5, 1); a3[2] = LDA(TA, 6, 1); a3[3] = LDA(TA, 7, 1); \
    SB0(); \
    LGK(4);  /* chunk3 done; chunk4 (4) in flight */ \
    __builtin_amdgcn_s_setprio(1); \
    GRP(a2, B1, 0); \
    __builtin_amdgcn_s_setprio(0); SB0(); \
    LGK(0);  /* chunk4 done */ \
    __builtin_amdgcn_s_setprio(1); \
    GRP(a3, B1, 4); \
    __builtin_amdgcn_s_setprio(0); \
    if (VM4) VMC(4); \
    if (VM0) VMC(0); \
    BAR(); \
  } while (0)

  for (int it = 0; it < 5; ++it) {  // 30 tiles: t = 0..29
    int t = it * 6;
    TILE(0, 0, 2, t + 0, 1, 1, 1, 0);
    TILE(1, 1, 0, t + 1, 1, 1, 1, 0);
    TILE(2, 0, 1, t + 2, 1, 1, 1, 0);
    TILE(0, 1, 2, t + 3, 1, 1, 1, 0);
    TILE(1, 0, 0, t + 4, 1, 1, 1, 0);
    TILE(2, 1, 1, t + 5, 1, 1, 1, 0);
  }
  // t=30 (TA=0,TB=0): stage B(31) only; drain all before tile31. t=31 (TA=1,TB=1).
  TILE(0, 0, 2, 30, 1, 0, 0, 1);
  TILE(1, 1, 0, 31, 0, 0, 0, 0);

  // epilogue: C/D layout col = lane&15, row = (lane>>4)*4 + reg
#pragma unroll
  for (int j = 0; j < 4; ++j) {
    int col = bn * 256 + wc * 64 + j * 16 + l15;
    float fb = (float)bq[col] * BSCALE;
    int ws = wsum[col];
#pragma unroll
    for (int i = 0; i < 8; ++i) {
      int rbase = bm * 256 + wr * 128 + i * 16 + hi * 4;
#pragma unroll
      for (int p = 0; p < 4; ++p)
        out[(size_t)(rbase + p) * Ndim + col] = (float)(acc[i][j][p] + ws) * OUT_SCALE + fb;
    }
  }
#undef TILE
#undef GRP
#undef ISSUE_A
#undef ISSUE_B
#undef LDA
#undef LDB
}

// ---------------- naive fallback (only if ws_size is unexpectedly small)
__global__ void fallback_kernel(const float* __restrict__ x, const int* __restrict__ wq,
                                const int* __restrict__ bq, float* __restrict__ out) {
  int col = blockIdx.x * 16 + (threadIdx.x & 15);
  int row = blockIdx.y * 16 + (threadIdx.x >> 4);
  const float* xr = x + (size_t)row * Kdim;
  const int* wr_ = wq + (size_t)col * Kdim;
  int acc = 0;
  for (int k = 0; k < Kdim; ++k) {
    int v = (int)rintf(xr[k] / ISF + 127.0f);
    v = v < 0 ? 0 : (v > 255 ? 255 : v);
    acc += (v - 127) * wr_[k];
  }
  out[(size_t)row * Ndim + col] = (float)acc * OUT_SCALE + (float)bq[col] * BSCALE;
}

extern "C" void kernel_launch(void* const* d_in, const int* in_sizes, int n_in,
                              void* d_out, int out_size, void* d_ws, size_t ws_size,
                              hipStream_t stream) {
  const float* x = (const float*)d_in[0];
  const int* wq = (const int*)d_in[1];
  const int* bq = (const int*)d_in[2];
  float* out = (float*)d_out;

  const size_t x8_bytes = (size_t)Mdim * Kdim;  // 32 MiB
  const size_t w8_bytes = (size_t)Ndim * Kdim;  // 16 MiB
  const size_t ws_need = x8_bytes + w8_bytes + (size_t)Ndim * sizeof(int);

  if (ws_size >= ws_need) {
    int8_t* x8 = (int8_t*)d_ws;
    int8_t* w8 = x8 + x8_bytes;
    int* wsum = (int*)(w8 + w8_bytes);

    quantize_x<<<2048, 256, 0, stream>>>(x, (int*)x8, Mdim * Kdim / 4);
    convert_w<<<Ndim, 256, 0, stream>>>(wq, (int*)w8, wsum);
    gemm_i8_pipe<<<(Mdim / 256) * (Ndim / 256), 512, 0, stream>>>(x8, w8, wsum, bq, out);
  } else {
    dim3 grid(Ndim / 16, Mdim / 16);
    fallback_kernel<<<grid, 256, 0, stream>>>(x, wq, bq, out);
  }
}